// Round 1
// baseline (15391.988 us; speedup 1.0000x reference)
//
#include <hip/hip_runtime.h>

#define D_ 512
#define FF_ 1024
#define L_ 4
#define A_ 32
#define B_ 1024
#define STEPS_ 64

// ---------------- one-time precompute: Wvo[l] = Wv[l] @ Wo[l] ----------------
__global__ __launch_bounds__(256) void wvo_kernel(
    const float* __restrict__ Wv, const float* __restrict__ Wo,
    float* __restrict__ Wvo)
{
    __shared__ float wvt[16][D_];             // 32 KB tile of Wv rows
    int bx  = blockIdx.x;
    int l   = bx >> 6;
    int rem = bx & 63;
    int k0  = (rem >> 1) * 16;
    int n   = (rem & 1) * 256 + threadIdx.x;

    const float* wvbase = Wv + (size_t)l * D_ * D_ + (size_t)k0 * D_;
    for (int idx = threadIdx.x; idx < 16 * D_; idx += 256)
        wvt[idx >> 9][idx & (D_ - 1)] = wvbase[idx];
    __syncthreads();

    float acc[16];
#pragma unroll
    for (int kk = 0; kk < 16; ++kk) acc[kk] = 0.f;

    const float* wop = Wo + (size_t)l * D_ * D_ + n;
    for (int m = 0; m < D_; m += 4) {
        float w0 = wop[(m + 0) * D_];
        float w1 = wop[(m + 1) * D_];
        float w2 = wop[(m + 2) * D_];
        float w3 = wop[(m + 3) * D_];
#pragma unroll
        for (int kk = 0; kk < 16; ++kk) {
            float4 wv4 = *(const float4*)&wvt[kk][m];
            acc[kk] += wv4.x * w0 + wv4.y * w1 + wv4.z * w2 + wv4.w * w3;
        }
    }
    float* outp = Wvo + (size_t)l * D_ * D_ + (size_t)k0 * D_ + n;
#pragma unroll
    for (int kk = 0; kk < 16; ++kk) outp[kk * D_] = acc[kk];
}

// ---------------- one-time precompute: bvo[l] = bv[l] @ Wo[l] + bo[l] ----------
__global__ __launch_bounds__(256) void bvo_kernel(
    const float* __restrict__ bv, const float* __restrict__ bo,
    const float* __restrict__ Wo, float* __restrict__ bvo)
{
    int l = blockIdx.x >> 1;
    int n = (blockIdx.x & 1) * 256 + threadIdx.x;
    float acc = bo[l * D_ + n];
    const float* wop = Wo + (size_t)l * D_ * D_ + n;
    const float* bvp = bv + l * D_;
    for (int m = 0; m < D_; ++m) acc += bvp[m] * wop[m * D_];
    bvo[l * D_ + n] = acc;
}

// ---------------- layer norm on 4 LDS rows (256 threads / sample) --------------
__device__ __forceinline__ void layer_norm_lds(
    float (*xb)[D_], float (*hb)[D_],
    const float* __restrict__ g, const float* __restrict__ bt,
    float (*red)[4][2], int sg, int r)
{
    float v0 = xb[sg][r], v1 = xb[sg][r + 256];
    float s  = v0 + v1;
    float ss = v0 * v0 + v1 * v1;
#pragma unroll
    for (int m = 1; m < 64; m <<= 1) {
        s  += __shfl_xor(s, m);
        ss += __shfl_xor(ss, m);
    }
    if ((r & 63) == 0) { red[sg][r >> 6][0] = s; red[sg][r >> 6][1] = ss; }
    __syncthreads();
    float S  = red[sg][0][0] + red[sg][1][0] + red[sg][2][0] + red[sg][3][0];
    float SS = red[sg][0][1] + red[sg][1][1] + red[sg][2][1] + red[sg][3][1];
    float mean = S * (1.f / 512.f);
    float var  = SS * (1.f / 512.f) - mean * mean;
    float rstd = 1.0f / sqrtf(var + 1e-5f);
    hb[sg][r]       = (v0 - mean) * rstd * g[r]       + bt[r];
    hb[sg][r + 256] = (v1 - mean) * rstd * g[r + 256] + bt[r + 256];
    __syncthreads();
}

// ---------------- persistent recurrence kernel: 4 samples per workgroup --------
__global__ __launch_bounds__(1024) void smain(
    const float* __restrict__ init_state,
    const float* __restrict__ acts,
    const float* __restrict__ Wa,  const float* __restrict__ ba,
    const float* __restrict__ ln1g, const float* __restrict__ ln1b,
    const float* __restrict__ ln2g, const float* __restrict__ ln2b,
    const float* __restrict__ Wf1, const float* __restrict__ bf1,
    const float* __restrict__ Wf2, const float* __restrict__ bf2,
    const float* __restrict__ lifth,
    const float* __restrict__ Wr,  const float* __restrict__ br,
    const float* __restrict__ Wvo, const float* __restrict__ bvo,
    float* __restrict__ out_states, float* __restrict__ out_rewards,
    float* __restrict__ out_final)
{
    __shared__ __align__(16) float xb[4][D_];    // residual stream x
    __shared__ __align__(16) float hb[4][D_];    // LN output
    __shared__ __align__(16) float sb[4][D_];    // carried state
    __shared__ __align__(16) float psc[4][FF_];  // k-half partial sums
    __shared__ float areg[4][A_];
    __shared__ float red[4][4][2];
    __shared__ int   fire_cnt;
    __shared__ int   fire_list[256];

    const int tid = threadIdx.x;
    const int sg  = tid >> 8;      // sample within WG (0..3)
    const int r   = tid & 255;
    const int b   = blockIdx.x * 4 + sg;

    sb[sg][r]       = init_state[(size_t)b * D_ + r];
    sb[sg][r + 256] = init_state[(size_t)b * D_ + r + 256];
    __syncthreads();

    for (int t = 0; t < STEPS_; ++t) {
        // ---- stage a[b][t][:] ----
        if (tid < 128) {
            int sg2 = tid >> 5, j = tid & 31;
            areg[sg2][j] = acts[((size_t)(blockIdx.x * 4 + sg2)) * (STEPS_ * A_) + t * A_ + j];
        }
        __syncthreads();

        // ---- x = state + a @ Wa + ba ----
        {
            float a0 = sb[sg][r]       + ba[r];
            float a1 = sb[sg][r + 256] + ba[r + 256];
#pragma unroll
            for (int j = 0; j < A_; ++j) {
                float av = areg[sg][j];
                a0 += av * Wa[j * D_ + r];
                a1 += av * Wa[j * D_ + r + 256];
            }
            xb[sg][r] = a0; xb[sg][r + 256] = a1;
        }
        __syncthreads();

        for (int l = 0; l < L_; ++l) {
            // ---- LN1 ----
            layer_norm_lds(xb, hb, ln1g + l * D_, ln1b + l * D_, red, sg, r);

            // ---- GEMV1: xb += hb @ Wvo[l] + bvo[l]  (attention block, o==v) ----
            {
                int n = tid & 511, half = tid >> 9;
                const float*  Wp = Wvo + (size_t)l * (D_ * D_) + (size_t)half * (256 * D_) + n;
                const float4* h0 = (const float4*)&hb[0][half * 256];
                const float4* h1 = (const float4*)&hb[1][half * 256];
                const float4* h2 = (const float4*)&hb[2][half * 256];
                const float4* h3 = (const float4*)&hb[3][half * 256];
                float a0 = 0.f, a1 = 0.f, a2 = 0.f, a3 = 0.f;
#pragma unroll 2
                for (int kb = 0; kb < 64; ++kb) {
                    float4 q0 = h0[kb], q1 = h1[kb], q2 = h2[kb], q3 = h3[kb];
                    float w0 = Wp[(4 * kb + 0) * D_];
                    float w1 = Wp[(4 * kb + 1) * D_];
                    float w2 = Wp[(4 * kb + 2) * D_];
                    float w3 = Wp[(4 * kb + 3) * D_];
                    a0 += q0.x * w0 + q0.y * w1 + q0.z * w2 + q0.w * w3;
                    a1 += q1.x * w0 + q1.y * w1 + q1.z * w2 + q1.w * w3;
                    a2 += q2.x * w0 + q2.y * w1 + q2.z * w2 + q2.w * w3;
                    a3 += q3.x * w0 + q3.y * w1 + q3.z * w2 + q3.w * w3;
                }
                if (half) { psc[0][n] = a0; psc[1][n] = a1; psc[2][n] = a2; psc[3][n] = a3; }
                __syncthreads();
                if (!half) {
                    float bb = bvo[l * D_ + n];
                    xb[0][n] += a0 + psc[0][n] + bb;
                    xb[1][n] += a1 + psc[1][n] + bb;
                    xb[2][n] += a2 + psc[2][n] + bb;
                    xb[3][n] += a3 + psc[3][n] + bb;
                }
                __syncthreads();
            }

            // ---- LN2 (also reset fire counter: safely between reader & writer) ----
            if (tid == 0) fire_cnt = 0;
            layer_norm_lds(xb, hb, ln2g + l * D_, ln2b + l * D_, red, sg, r);

            // ---- GEMV2: pre = hb @ Wf1[l] + bf1[l] - 2.0 ; record fired units ----
            {
                int p = tid & 511, half = tid >> 9;
                const float2* Wp = (const float2*)(Wf1 + (size_t)l * (D_ * FF_) + (size_t)half * (256 * FF_)) + p;
                const float4* h0 = (const float4*)&hb[0][half * 256];
                const float4* h1 = (const float4*)&hb[1][half * 256];
                const float4* h2 = (const float4*)&hb[2][half * 256];
                const float4* h3 = (const float4*)&hb[3][half * 256];
                float acc[4][2];
#pragma unroll
                for (int i = 0; i < 4; ++i) { acc[i][0] = 0.f; acc[i][1] = 0.f; }
#pragma unroll 2
                for (int kb = 0; kb < 64; ++kb) {
                    float4 q0 = h0[kb], q1 = h1[kb], q2 = h2[kb], q3 = h3[kb];
                    float2 w0 = Wp[(4 * kb + 0) * 512];
                    float2 w1 = Wp[(4 * kb + 1) * 512];
                    float2 w2 = Wp[(4 * kb + 2) * 512];
                    float2 w3 = Wp[(4 * kb + 3) * 512];
                    acc[0][0] += q0.x * w0.x + q0.y * w1.x + q0.z * w2.x + q0.w * w3.x;
                    acc[0][1] += q0.x * w0.y + q0.y * w1.y + q0.z * w2.y + q0.w * w3.y;
                    acc[1][0] += q1.x * w0.x + q1.y * w1.x + q1.z * w2.x + q1.w * w3.x;
                    acc[1][1] += q1.x * w0.y + q1.y * w1.y + q1.z * w2.y + q1.w * w3.y;
                    acc[2][0] += q2.x * w0.x + q2.y * w1.x + q2.z * w2.x + q2.w * w3.x;
                    acc[2][1] += q2.x * w0.y + q2.y * w1.y + q2.z * w2.y + q2.w * w3.y;
                    acc[3][0] += q3.x * w0.x + q3.y * w1.x + q3.z * w2.x + q3.w * w3.x;
                    acc[3][1] += q3.x * w0.y + q3.y * w1.y + q3.z * w2.y + q3.w * w3.y;
                }
                if (half) {
#pragma unroll
                    for (int i = 0; i < 4; ++i) {
                        psc[i][2 * p]     = acc[i][0];
                        psc[i][2 * p + 1] = acc[i][1];
                    }
                }
                __syncthreads();
                if (!half) {
                    float bb0 = bf1[l * FF_ + 2 * p]     - 2.0f;
                    float bb1 = bf1[l * FF_ + 2 * p + 1] - 2.0f;
#pragma unroll
                    for (int i = 0; i < 4; ++i) {
                        float pr0 = acc[i][0] + psc[i][2 * p]     + bb0;
                        float pr1 = acc[i][1] + psc[i][2 * p + 1] + bb1;
                        if (pr0 > 0.f) {
                            int idx = atomicAdd(&fire_cnt, 1);
                            if (idx < 256) fire_list[idx] = (i << 12) | (2 * p);
                        }
                        if (pr1 > 0.f) {
                            int idx = atomicAdd(&fire_cnt, 1);
                            if (idx < 256) fire_list[idx] = (i << 12) | (2 * p + 1);
                        }
                    }
                }
                __syncthreads();
            }

            // ---- sparse s @ Wf2 (rare events) + bf2 ----
            {
                int cnt = fire_cnt; if (cnt > 256) cnt = 256;
                if (cnt > 0) {
                    for (int e = 0; e < cnt; ++e) {
                        int ent = fire_list[e];
                        int i = ent >> 12, n = ent & 4095;
                        if (tid < D_) xb[i][tid] += Wf2[(size_t)l * (FF_ * D_) + (size_t)n * D_ + tid];
                    }
                    __syncthreads();
                }
                xb[sg][r]       += bf2[l * D_ + r];
                xb[sg][r + 256] += bf2[l * D_ + r + 256];
            }
            __syncthreads();
        } // layers

        // ---- LIF spike, outputs, reward ----
        {
            float x0 = xb[sg][r], x1 = xb[sg][r + 256];
            float s0 = (x0 > lifth[r])       ? 1.0f : 0.0f;
            float s1 = (x1 > lifth[r + 256]) ? 1.0f : 0.0f;
            sb[sg][r] = s0; sb[sg][r + 256] = s1;
            size_t so = ((size_t)b * STEPS_ + t) * D_;
            out_states[so + r]       = s0;
            out_states[so + r + 256] = s1;

            float rs = s0 * Wr[r] + s1 * Wr[r + 256];
#pragma unroll
            for (int m = 1; m < 64; m <<= 1) rs += __shfl_xor(rs, m);
            if ((r & 63) == 0) red[sg][r >> 6][0] = rs;
            __syncthreads();
            if (r == 0)
                out_rewards[(size_t)b * STEPS_ + t] =
                    red[sg][0][0] + red[sg][1][0] + red[sg][2][0] + red[sg][3][0] + br[0];
        }
        __syncthreads();
    } // steps

    out_final[(size_t)b * D_ + r]       = sb[sg][r];
    out_final[(size_t)b * D_ + r + 256] = sb[sg][r + 256];
}

extern "C" void kernel_launch(void* const* d_in, const int* in_sizes, int n_in,
                              void* d_out, int out_size, void* d_ws, size_t ws_size,
                              hipStream_t stream) {
    (void)in_sizes; (void)n_in; (void)out_size; (void)ws_size;
    const float* init_state = (const float*)d_in[0];
    const float* acts  = (const float*)d_in[1];
    const float* Wa    = (const float*)d_in[2];
    const float* ba    = (const float*)d_in[3];
    const float* ln1g  = (const float*)d_in[4];
    const float* ln1b  = (const float*)d_in[5];
    // d_in[6..9] = Wq, bq, Wk, bk: provably dead (softmax over length-1 axis)
    const float* Wv    = (const float*)d_in[10];
    const float* bv    = (const float*)d_in[11];
    const float* Wo    = (const float*)d_in[12];
    const float* bo    = (const float*)d_in[13];
    const float* ln2g  = (const float*)d_in[14];
    const float* ln2b  = (const float*)d_in[15];
    const float* Wf1   = (const float*)d_in[16];
    const float* bf1   = (const float*)d_in[17];
    const float* Wf2   = (const float*)d_in[18];
    const float* bf2   = (const float*)d_in[19];
    const float* lifth = (const float*)d_in[20];
    const float* Wr    = (const float*)d_in[21];
    const float* br    = (const float*)d_in[22];

    float* ws  = (float*)d_ws;
    float* Wvo = ws;                       // 4*512*512 floats
    float* bvo = ws + (size_t)L_ * D_ * D_; // 4*512 floats

    float* out         = (float*)d_out;
    float* out_states  = out;
    float* out_rewards = out + (size_t)B_ * STEPS_ * D_;
    float* out_final   = out_rewards + (size_t)B_ * STEPS_;

    wvo_kernel<<<dim3(256), dim3(256), 0, stream>>>(Wv, Wo, Wvo);
    bvo_kernel<<<dim3(8),   dim3(256), 0, stream>>>(bv, bo, Wo, bvo);
    smain<<<dim3(256), dim3(1024), 0, stream>>>(
        init_state, acts, Wa, ba, ln1g, ln1b, ln2g, ln2b,
        Wf1, bf1, Wf2, bf2, lifth, Wr, br, Wvo, bvo,
        out_states, out_rewards, out_final);
}